// Round 1
// baseline (563.073 us; speedup 1.0000x reference)
//
#include <hip/hip_runtime.h>
#include <hip/hip_bf16.h>

#define S_LEN 2048
#define D_K   64
#define N_H   16
#define N_B   4

typedef __attribute__((ext_vector_type(8))) short bf16x8;
typedef __attribute__((ext_vector_type(4))) float f32x4;

__device__ inline unsigned short f2bf(float x) {
    unsigned int u = __builtin_bit_cast(unsigned int, x);
    return (unsigned short)((u + 0x7fffu + ((u >> 16) & 1u)) >> 16);
}

__device__ inline bf16x8 cvt8(const float* __restrict__ p) {
    float4 a = *(const float4*)p;
    float4 b = *(const float4*)(p + 4);
    bf16x8 f;
    f[0] = (short)f2bf(a.x); f[1] = (short)f2bf(a.y);
    f[2] = (short)f2bf(a.z); f[3] = (short)f2bf(a.w);
    f[4] = (short)f2bf(b.x); f[5] = (short)f2bf(b.y);
    f[6] = (short)f2bf(b.z); f[7] = (short)f2bf(b.w);
    return f;
}

__global__ void attn_fwd_kernel(const float* __restrict__ q,
                                const float* __restrict__ k,
                                const float* __restrict__ v,
                                const int*   __restrict__ mask,
                                float*       __restrict__ out) {
    const int qblk = blockIdx.x;   // 0..31 (S/64)
    const int bh   = blockIdx.y;   // 0..63 (B*H)
    const int b    = bh >> 4;      // /H
    const int t    = threadIdx.x;
    const int lane = t & 63;
    const int wq   = t >> 6;       // wave id 0..3

    __shared__ __align__(16) short kbuf[64 * 64];
    __shared__ __align__(16) short vbuf[64 * 64];
    __shared__ __align__(16) short pbuf[4][16 * 64];

    const float scale = 0.125f;
    const long  base  = (long)bh * S_LEN * D_K;
    const int   qrow0 = qblk * 64 + wq * 16;

    // ---- Q fragments (A-layout: row = lane&15, k = (lane>>4)*8 + j) ----
    bf16x8 qf[2];
    {
        int r  = qrow0 + (lane & 15);
        int kb = (lane >> 4) * 8;
        const float* qp = q + base + (long)r * D_K + kb;
        qf[0] = cvt8(qp);
        qf[1] = cvt8(qp + 32);
    }

    f32x4 o[4];
#pragma unroll
    for (int i = 0; i < 4; ++i) o[i] = (f32x4){0.f, 0.f, 0.f, 0.f};
    float mrun[4], lrun[4];
#pragma unroll
    for (int r = 0; r < 4; ++r) { mrun[r] = -1e30f; lrun[r] = 0.f; }

    const int* maskb = mask + b * S_LEN;
    short* pw = &pbuf[wq][0];

    for (int kv0 = 0; kv0 < S_LEN; kv0 += 64) {
        __syncthreads();   // previous tile fully consumed before overwrite

        // ---- stage K,V tile (64x64 fp32 -> bf16, swizzled LDS) ----
#pragma unroll
        for (int c = t; c < 512; c += 256) {
            int row = c >> 3, col8 = c & 7;
            const float* kp = k + base + (long)(kv0 + row) * D_K + col8 * 8;
            const float* vp = v + base + (long)(kv0 + row) * D_K + col8 * 8;
            bf16x8 fk = cvt8(kp);
            bf16x8 fv = cvt8(vp);
            int byte = row * 128 + col8 * 16;
            *(bf16x8*)((char*)kbuf + (byte ^ ((row & 7) << 4)))        = fk;
            *(bf16x8*)((char*)vbuf + (byte ^ (((row >> 3) & 3) << 5))) = fv;
        }
        __syncthreads();

        // ---- S = Q K^T (per wave: 16 q-rows x 64 keys) ----
        f32x4 s[4];
#pragma unroll
        for (int ct = 0; ct < 4; ++ct) {
            f32x4 acc = (f32x4){0.f, 0.f, 0.f, 0.f};
            int krow    = ct * 16 + (lane & 15);
            int rowbyte = krow * 128;
            int swz     = (krow & 7) << 4;
#pragma unroll
            for (int kk = 0; kk < 2; ++kk) {
                int byte = (rowbyte + (kk * 32 + (lane >> 4) * 8) * 2) ^ swz;
                bf16x8 kf = *(const bf16x8*)((const char*)kbuf + byte);
                acc = __builtin_amdgcn_mfma_f32_16x16x32_bf16(qf[kk], kf, acc, 0, 0, 0);
            }
            s[ct] = acc;
        }

        // ---- scale + mask (C-layout: col = lane&15 = key, row = (lane>>4)*4+r) ----
#pragma unroll
        for (int ct = 0; ct < 4; ++ct) {
            int key  = kv0 + ct * 16 + (lane & 15);
            bool mok = (maskb[key] != 0);
#pragma unroll
            for (int r = 0; r < 4; ++r)
                s[ct][r] = mok ? s[ct][r] * scale : -1e9f;
        }

        // ---- online softmax: per-row max over 64 keys ----
        float tmax[4];
#pragma unroll
        for (int r = 0; r < 4; ++r)
            tmax[r] = fmaxf(fmaxf(s[0][r], s[1][r]), fmaxf(s[2][r], s[3][r]));
#pragma unroll
        for (int d = 1; d < 16; d <<= 1)
#pragma unroll
            for (int r = 0; r < 4; ++r)
                tmax[r] = fmaxf(tmax[r], __shfl_xor(tmax[r], d, 64));

        float alpha[4], rsum[4];
#pragma unroll
        for (int r = 0; r < 4; ++r) {
            float mnew = fmaxf(mrun[r], tmax[r]);
            alpha[r]   = __expf(mrun[r] - mnew);
            mrun[r]    = mnew;
            rsum[r]    = 0.f;
        }

        // ---- P = exp(s - m), write to per-wave swizzled LDS ----
#pragma unroll
        for (int ct = 0; ct < 4; ++ct) {
#pragma unroll
            for (int r = 0; r < 4; ++r) {
                float p = __expf(s[ct][r] - mrun[r]);
                rsum[r] += p;
                int prow = (lane >> 4) * 4 + r;
                int pcol = ct * 16 + (lane & 15);
                int byte = (prow * 128 + pcol * 2) ^ ((prow & 7) << 4);
                *(short*)((char*)pw + byte) = (short)f2bf(p);
            }
        }
#pragma unroll
        for (int d = 1; d < 16; d <<= 1)
#pragma unroll
            for (int r = 0; r < 4; ++r)
                rsum[r] += __shfl_xor(rsum[r], d, 64);
#pragma unroll
        for (int r = 0; r < 4; ++r)
            lrun[r] = lrun[r] * alpha[r] + rsum[r];
#pragma unroll
        for (int dc = 0; dc < 4; ++dc)
#pragma unroll
            for (int r = 0; r < 4; ++r)
                o[dc][r] *= alpha[r];

        // ---- O += P V ----
#pragma unroll
        for (int dc = 0; dc < 4; ++dc) {
            int vcol = dc * 16 + (lane & 15);
#pragma unroll
            for (int kk = 0; kk < 2; ++kk) {
                int prow = lane & 15;
                int pbyte = (prow * 128 + (kk * 32 + (lane >> 4) * 8) * 2) ^ ((prow & 7) << 4);
                bf16x8 pf = *(const bf16x8*)((const char*)pw + pbyte);
                bf16x8 vf;
#pragma unroll
                for (int j = 0; j < 8; ++j) {
                    int vrow = kk * 32 + (lane >> 4) * 8 + j;
                    int vb   = (vrow * 128 + vcol * 2) ^ (((vrow >> 3) & 3) << 5);
                    vf[j] = *(const short*)((const char*)vbuf + vb);
                }
                o[dc] = __builtin_amdgcn_mfma_f32_16x16x32_bf16(pf, vf, o[dc], 0, 0, 0);
            }
        }
    }

    // ---- epilogue: out = o / l ----
#pragma unroll
    for (int dc = 0; dc < 4; ++dc) {
#pragma unroll
        for (int r = 0; r < 4; ++r) {
            int row = qrow0 + (lane >> 4) * 4 + r;
            int col = dc * 16 + (lane & 15);
            out[base + (long)row * D_K + col] = o[dc][r] / lrun[r];
        }
    }
}

extern "C" void kernel_launch(void* const* d_in, const int* in_sizes, int n_in,
                              void* d_out, int out_size, void* d_ws, size_t ws_size,
                              hipStream_t stream) {
    const float* q    = (const float*)d_in[0];
    const float* k    = (const float*)d_in[1];
    const float* v    = (const float*)d_in[2];
    const int*   mask = (const int*)d_in[3];
    float*       out  = (float*)d_out;

    dim3 grid(S_LEN / 64, N_B * N_H);
    attn_fwd_kernel<<<grid, 256, 0, stream>>>(q, k, v, mask, out);
}

// Round 2
// 261.579 us; speedup vs baseline: 2.1526x; 2.1526x over previous
//
#include <hip/hip_runtime.h>
#include <hip/hip_bf16.h>

#define S_LEN 2048
#define D_K   64
#define N_H   16
#define N_B   4

typedef __attribute__((ext_vector_type(8))) short bf16x8;
typedef __attribute__((ext_vector_type(4))) float f32x4;

__device__ inline short f2bfs(float x) {
    __hip_bfloat16 h = __float2bfloat16(x);
    return __builtin_bit_cast(short, h);
}

__device__ inline bf16x8 cvt8(const float* __restrict__ p) {
    float4 a = *(const float4*)p;
    float4 b = *(const float4*)(p + 4);
    bf16x8 f;
    f[0] = f2bfs(a.x); f[1] = f2bfs(a.y);
    f[2] = f2bfs(a.z); f[3] = f2bfs(a.w);
    f[4] = f2bfs(b.x); f[5] = f2bfs(b.y);
    f[6] = f2bfs(b.z); f[7] = f2bfs(b.w);
    return f;
}

__device__ inline int vswz(int d, int byte) {
    return byte ^ ((((d & 7) ^ ((d >> 3) & 7)) << 4));
}

__global__ void attn_fwd_kernel(const float* __restrict__ q,
                                const float* __restrict__ k,
                                const float* __restrict__ v,
                                const int*   __restrict__ mask,
                                float*       __restrict__ out) {
    // XCD-aware bijective swizzle: all 32 q-blocks of a bh on one XCD,
    // qblk fastest in time within the XCD (K/V stays L2-resident).
    const int id      = blockIdx.x;            // 0..2047, XCD = id % 8
    const int logical = (id & 7) * 256 + (id >> 3);
    const int bh      = logical >> 5;          // 0..63
    const int qblk    = logical & 31;          // 0..31
    const int b       = bh >> 4;               // /H
    const int t       = threadIdx.x;
    const int lane    = t & 63;
    const int wq      = t >> 6;                // wave id 0..3
    const int hi      = lane >> 4;             // 0..3
    const int lo      = lane & 15;

    __shared__ __align__(16) short kbuf[64 * 64];
    __shared__ __align__(16) short vtbuf[64 * 64];   // transposed: [d][kv]
    __shared__ __align__(16) short pbuf[4][16 * 64];
    __shared__ float mbias[S_LEN];                   // 0 or -1e9*log2e

    const float LOG2E  = 1.44269504f;
    const float scale2 = 0.125f * LOG2E;             // 1/sqrt(64) * log2(e)
    const long  base   = (long)bh * S_LEN * D_K;
    const int   qrow0  = qblk * 64 + wq * 16;

    // ---- mask bias -> LDS (once per block) ----
    {
        const int* maskb = mask + b * S_LEN;
        for (int i = t; i < S_LEN; i += 256)
            mbias[i] = maskb[i] ? 0.f : -1.442695e9f;
    }

    // ---- Q fragments (A-layout: row = lane&15, k = hi*8 + j) ----
    bf16x8 qf[2];
    {
        int r  = qrow0 + lo;
        const float* qp = q + base + (long)r * D_K + hi * 8;
        qf[0] = cvt8(qp);
        qf[1] = cvt8(qp + 32);
    }

    f32x4 o[4];
#pragma unroll
    for (int i = 0; i < 4; ++i) o[i] = (f32x4){0.f, 0.f, 0.f, 0.f};
    float mrun[4], lrun[4];
#pragma unroll
    for (int r = 0; r < 4; ++r) { mrun[r] = -1e30f; lrun[r] = 0.f; }

    short* pw = &pbuf[wq][0];

    for (int kv0 = 0; kv0 < S_LEN; kv0 += 64) {
        __syncthreads();   // previous tile fully consumed before overwrite

        // ---- stage K (row-major swizzled) and V (transposed swizzled) ----
#pragma unroll
        for (int c = t; c < 512; c += 256) {
            int row = c >> 3, col8 = c & 7;
            const float* kp = k + base + (long)(kv0 + row) * D_K + col8 * 8;
            const float* vp = v + base + (long)(kv0 + row) * D_K + col8 * 8;
            bf16x8 fk = cvt8(kp);
            bf16x8 fv = cvt8(vp);
            int kb = row * 128 + col8 * 16;
            *(bf16x8*)((char*)kbuf + (kb ^ ((row & 7) << 4))) = fk;
#pragma unroll
            for (int j = 0; j < 8; ++j) {
                int d = col8 * 8 + j;
                *(short*)((char*)vtbuf + vswz(d, d * 128 + row * 2)) = fv[j];
            }
        }
        __syncthreads();

        // ---- S = Q K^T ----
        f32x4 s[4];
#pragma unroll
        for (int ct = 0; ct < 4; ++ct) {
            f32x4 acc = (f32x4){0.f, 0.f, 0.f, 0.f};
            int krow    = ct * 16 + lo;
            int rowbyte = krow * 128;
            int swz     = (krow & 7) << 4;
#pragma unroll
            for (int kk = 0; kk < 2; ++kk) {
                int byte = (rowbyte + (kk * 32 + hi * 8) * 2) ^ swz;
                bf16x8 kf = *(const bf16x8*)((const char*)kbuf + byte);
                acc = __builtin_amdgcn_mfma_f32_16x16x32_bf16(qf[kk], kf, acc, 0, 0, 0);
            }
            s[ct] = acc;
        }

        // ---- scale + mask bias (C-layout: col = lo = key, row = hi*4+r) ----
#pragma unroll
        for (int ct = 0; ct < 4; ++ct) {
            float bias = mbias[kv0 + ct * 16 + lo];
#pragma unroll
            for (int r = 0; r < 4; ++r)
                s[ct][r] = fmaf(s[ct][r], scale2, bias);
        }

        // ---- online softmax (base-2 domain) ----
        float tmax[4];
#pragma unroll
        for (int r = 0; r < 4; ++r)
            tmax[r] = fmaxf(fmaxf(s[0][r], s[1][r]), fmaxf(s[2][r], s[3][r]));
#pragma unroll
        for (int d = 1; d < 16; d <<= 1)
#pragma unroll
            for (int r = 0; r < 4; ++r)
                tmax[r] = fmaxf(tmax[r], __shfl_xor(tmax[r], d, 64));

        float alpha[4], rsum[4];
#pragma unroll
        for (int r = 0; r < 4; ++r) {
            float mnew = fmaxf(mrun[r], tmax[r]);
            alpha[r]   = exp2f(mrun[r] - mnew);
            mrun[r]    = mnew;
            rsum[r]    = 0.f;
        }

        // ---- P = exp2(s - m) -> per-wave swizzled LDS ----
#pragma unroll
        for (int ct = 0; ct < 4; ++ct) {
#pragma unroll
            for (int r = 0; r < 4; ++r) {
                float p = exp2f(s[ct][r] - mrun[r]);
                rsum[r] += p;
                int prow = hi * 4 + r;
                int byte = (prow * 128 + (ct * 16 + lo) * 2) ^ ((prow & 7) << 4);
                *(short*)((char*)pw + byte) = f2bfs(p);
            }
        }
#pragma unroll
        for (int d = 1; d < 16; d <<= 1)
#pragma unroll
            for (int r = 0; r < 4; ++r)
                rsum[r] += __shfl_xor(rsum[r], d, 64);
#pragma unroll
        for (int r = 0; r < 4; ++r)
            lrun[r] = lrun[r] * alpha[r] + rsum[r];
#pragma unroll
        for (int dc = 0; dc < 4; ++dc)
#pragma unroll
            for (int r = 0; r < 4; ++r)
                o[dc][r] *= alpha[r];

        // ---- O += P V  (V^T b128 fragments) ----
#pragma unroll
        for (int dc = 0; dc < 4; ++dc) {
            int d = dc * 16 + lo;
#pragma unroll
            for (int kk = 0; kk < 2; ++kk) {
                int prow  = lo;
                int pbyte = (prow * 128 + (kk * 32 + hi * 8) * 2) ^ ((prow & 7) << 4);
                bf16x8 pf = *(const bf16x8*)((const char*)pw + pbyte);
                bf16x8 vf = *(const bf16x8*)((const char*)vtbuf +
                              vswz(d, d * 128 + (kk * 32 + hi * 8) * 2));
                o[dc] = __builtin_amdgcn_mfma_f32_16x16x32_bf16(pf, vf, o[dc], 0, 0, 0);
            }
        }
    }

    // ---- epilogue: out = o / l ----
#pragma unroll
    for (int r = 0; r < 4; ++r) {
        float rl = 1.0f / lrun[r];
        int row = qrow0 + hi * 4 + r;
#pragma unroll
        for (int dc = 0; dc < 4; ++dc) {
            int col = dc * 16 + lo;
            out[base + (long)row * D_K + col] = o[dc][r] * rl;
        }
    }
}

extern "C" void kernel_launch(void* const* d_in, const int* in_sizes, int n_in,
                              void* d_out, int out_size, void* d_ws, size_t ws_size,
                              hipStream_t stream) {
    const float* q    = (const float*)d_in[0];
    const float* k    = (const float*)d_in[1];
    const float* v    = (const float*)d_in[2];
    const int*   mask = (const int*)d_in[3];
    float*       out  = (float*)d_out;

    dim3 grid((S_LEN / 64) * N_B * N_H);   // 2048 blocks, 1-D for XCD swizzle
    attn_fwd_kernel<<<grid, 256, 0, stream>>>(q, k, v, mask, out);
}

// Round 3
// 186.003 us; speedup vs baseline: 3.0272x; 1.4063x over previous
//
#include <hip/hip_runtime.h>
#include <hip/hip_bf16.h>

#define S_LEN 2048
#define D_K   64
#define N_H   16
#define N_B   4
#define KVB   64
#define NT    (S_LEN / KVB)
#define QPB   128                 // q-rows per block (4 waves x 32)
#define NQB   (S_LEN / QPB)       // 16

typedef __attribute__((ext_vector_type(8)))  short bf16x8;
typedef __attribute__((ext_vector_type(16))) float f32x16;
typedef unsigned int u32;
typedef __attribute__((ext_vector_type(4))) u32 u32x4;

__device__ inline short f2bfs(float x) {
    __hip_bfloat16 h = __float2bfloat16(x);
    return __builtin_bit_cast(short, h);
}

__device__ inline bf16x8 cvt8(const float* __restrict__ p) {
    float4 a = *(const float4*)p;
    float4 b = *(const float4*)(p + 4);
    bf16x8 f;
    f[0] = f2bfs(a.x); f[1] = f2bfs(a.y);
    f[2] = f2bfs(a.z); f[3] = f2bfs(a.w);
    f[4] = f2bfs(b.x); f[5] = f2bfs(b.y);
    f[6] = f2bfs(b.z); f[7] = f2bfs(b.w);
    return f;
}

// V^T swizzle: spreads row-d b128 reads & staging writes across banks
__device__ inline int vswz(int d) { return ((d & 7) ^ ((d >> 3) & 7)) << 4; }

__global__ __launch_bounds__(256)
void attn_fwd(const float* __restrict__ q, const float* __restrict__ k,
              const float* __restrict__ v, const int* __restrict__ mask,
              float* __restrict__ out) {
    // XCD-aware bijective swizzle (1024 = 8*128): 8 bh-groups per XCD,
    // qblk fastest in time so K/V of one bh stays L2-resident.
    const int id      = blockIdx.x;
    const int logical = (id & 7) * 128 + (id >> 3);
    const int bh      = logical >> 4;
    const int qblk    = logical & 15;
    const int b       = bh >> 4;
    const int t       = threadIdx.x;
    const int lane    = t & 63;
    const int wq      = t >> 6;     // wave 0..3
    const int hb      = lane >> 5;  // half-wave 0/1
    const int ql      = lane & 31;

    __shared__ __align__(16) short kbuf[KVB * D_K];   // [key][dk], swizzled
    __shared__ __align__(16) short vtbuf[D_K * KVB];  // [d][key],  swizzled
    __shared__ float mbias[S_LEN];

    const float scale2 = 0.125f * 1.44269504f;        // 1/sqrt(64)*log2(e)
    const long  base   = (long)bh * S_LEN * D_K;
    const int   qrow0  = qblk * QPB + wq * 32;

    // ---- mask bias -> LDS ----
    {
        const int* mb = mask + b * S_LEN;
        for (int i = t; i < S_LEN; i += 256)
            mbias[i] = mb[i] ? 0.f : -1.442695e9f;
    }

    // ---- Q fragments: B-layout col=ql(qrow), k = kd*16 + hb*8 + j ----
    bf16x8 qf[4];
    {
        const float* qp = q + base + (long)(qrow0 + ql) * D_K + hb * 8;
#pragma unroll
        for (int kd = 0; kd < 4; ++kd) qf[kd] = cvt8(qp + kd * 16);
    }

    f32x16 o0, o1;
#pragma unroll
    for (int r = 0; r < 16; ++r) { o0[r] = 0.f; o1[r] = 0.f; }
    float mrun = -1e30f, lrun = 0.f;

    // ---- staging registers (2-phase pipeline) ----
    const int srow = t >> 3;   // +u2*32
    const int scol = t & 7;
    float4 kr[2][2], vr[2][2];

    auto LOADT = [&](int kv0) {
#pragma unroll
        for (int u2 = 0; u2 < 2; ++u2) {
            int row = srow + u2 * 32;
            const float* kp = k + base + (long)(kv0 + row) * D_K + scol * 8;
            const float* vp = v + base + (long)(kv0 + row) * D_K + scol * 8;
            kr[u2][0] = *(const float4*)kp; kr[u2][1] = *(const float4*)(kp + 4);
            vr[u2][0] = *(const float4*)vp; vr[u2][1] = *(const float4*)(vp + 4);
        }
    };

    LOADT(0);

    for (int tt = 0; tt < NT; ++tt) {
        const int kv0 = tt * KVB;
        __syncthreads();                       // prev compute done with bufs

        // ---- write staged regs -> LDS (cvt fp32->bf16) ----
#pragma unroll
        for (int u2 = 0; u2 < 2; ++u2) {
            int row = srow + u2 * 32;
            bf16x8 fk, fv;
#pragma unroll
            for (int j = 0; j < 4; ++j) {
                fk[j]     = f2bfs(((const float*)&kr[u2][0])[j]);
                fk[j + 4] = f2bfs(((const float*)&kr[u2][1])[j]);
                fv[j]     = f2bfs(((const float*)&vr[u2][0])[j]);
                fv[j + 4] = f2bfs(((const float*)&vr[u2][1])[j]);
            }
            int kb = (row * 128 + scol * 16) ^ ((row & 7) << 4);
            *(bf16x8*)((char*)kbuf + kb) = fk;
#pragma unroll
            for (int j = 0; j < 8; ++j) {
                int d  = scol * 8 + j;
                int vb = (d * 128 + row * 2) ^ vswz(d);
                *(short*)((char*)vtbuf + vb) = fv[j];
            }
        }
        if (tt + 1 < NT) LOADT(kv0 + KVB);     // async, in flight over compute
        __syncthreads();                       // staging visible

        // ---- S^T = K Q^T (swapped): lane owns qrow=ql, keys crow(r,hb) ----
        f32x16 st[2];
#pragma unroll
        for (int kb32 = 0; kb32 < 2; ++kb32) {
            f32x16 acc;
#pragma unroll
            for (int r = 0; r < 16; ++r) acc[r] = 0.f;
            int krow = kb32 * 32 + ql;
            int rb = krow * 128, sz = (krow & 7) << 4;
#pragma unroll
            for (int kd = 0; kd < 4; ++kd) {
                bf16x8 kf = *(const bf16x8*)((const char*)kbuf +
                              ((rb + (kd * 16 + hb * 8) * 2) ^ sz));
                acc = __builtin_amdgcn_mfma_f32_32x32x16_bf16(kf, qf[kd], acc, 0, 0, 0);
            }
            st[kb32] = acc;
        }

        // ---- scale + mask bias; key = kv0 + kb32*32 + (r&3)+8(r>>2)+4hb ----
#pragma unroll
        for (int kb32 = 0; kb32 < 2; ++kb32)
#pragma unroll
            for (int r = 0; r < 16; ++r) {
                int key = kv0 + kb32 * 32 + (r & 3) + 8 * (r >> 2) + 4 * hb;
                st[kb32][r] = fmaf(st[kb32][r], scale2, mbias[key]);
            }

        // ---- row max: in-register tree + one cross-half swap ----
        float m8[8];
#pragma unroll
        for (int i = 0; i < 8; ++i)
            m8[i] = fmaxf(fmaxf(st[0][i], st[0][i + 8]),
                          fmaxf(st[1][i], st[1][i + 8]));
        float tmax = fmaxf(fmaxf(fmaxf(m8[0], m8[1]), fmaxf(m8[2], m8[3])),
                           fmaxf(fmaxf(m8[4], m8[5]), fmaxf(m8[6], m8[7])));
        tmax = fmaxf(tmax, __shfl_xor(tmax, 32, 64));

        // ---- defer-max (T13): rescale only when max grows past THR ----
        if (__any(tmax > mrun + 10.0f)) {
            float mnew = fmaxf(mrun, tmax);
            float al   = __builtin_amdgcn_exp2f(mrun - mnew);
            mrun = mnew;
            lrun *= al;
#pragma unroll
            for (int r = 0; r < 16; ++r) {
                float ar = __shfl(al, (r & 3) + 8 * (r >> 2) + 4 * hb, 64);
                o0[r] *= ar; o1[r] *= ar;
            }
        }

        // ---- P = exp2(s - m), pack to bf16 pairs ----
        u32 w[2][8];
        float rs = 0.f;
#pragma unroll
        for (int kb32 = 0; kb32 < 2; ++kb32)
#pragma unroll
            for (int m = 0; m < 8; ++m) {
                float p0 = __builtin_amdgcn_exp2f(st[kb32][2 * m]     - mrun);
                float p1 = __builtin_amdgcn_exp2f(st[kb32][2 * m + 1] - mrun);
                rs += p0 + p1;
                w[kb32][m] = (u32)(unsigned short)f2bfs(p0) |
                             ((u32)(unsigned short)f2bfs(p1) << 16);
            }
        rs += __shfl_xor(rs, 32, 64);
        lrun += rs;

        // ---- PV: A-frag via permlane32_swap, B = V^T b128 reads ----
#pragma unroll
        for (int kb = 0; kb < 4; ++kb) {
            int c = kb >> 1, a2 = (kb & 1) * 4;
            u32 x0 = w[c][a2 + 0], y0 = w[c][a2 + 2];
            u32 x1 = w[c][a2 + 1], y1 = w[c][a2 + 3];
            asm("v_permlane32_swap_b32 %0, %1" : "+v"(x0), "+v"(y0));
            asm("v_permlane32_swap_b32 %0, %1" : "+v"(x1), "+v"(y1));
            u32x4 av = {x0, x1, y0, y1};       // j01, j23, j45, j67
            bf16x8 pa = __builtin_bit_cast(bf16x8, av);
#pragma unroll
            for (int dn = 0; dn < 2; ++dn) {
                int d  = dn * 32 + ql;
                int vb = (d * 128 + (kb * 16 + hb * 8) * 2) ^ vswz(d);
                bf16x8 vf = *(const bf16x8*)((const char*)vtbuf + vb);
                if (dn == 0)
                    o0 = __builtin_amdgcn_mfma_f32_32x32x16_bf16(pa, vf, o0, 0, 0, 0);
                else
                    o1 = __builtin_amdgcn_mfma_f32_32x32x16_bf16(pa, vf, o1, 0, 0, 0);
            }
        }
    }

    // ---- epilogue: out[qrow][d] = o / l ----
    float rl = 1.0f / lrun;
#pragma unroll
    for (int r = 0; r < 16; ++r) {
        int   cr  = (r & 3) + 8 * (r >> 2) + 4 * hb;
        float rlr = __shfl(rl, cr, 64);
        long  rowb = base + (long)(qrow0 + cr) * D_K;
        out[rowb + ql]      = o0[r] * rlr;
        out[rowb + 32 + ql] = o1[r] * rlr;
    }
}

extern "C" void kernel_launch(void* const* d_in, const int* in_sizes, int n_in,
                              void* d_out, int out_size, void* d_ws, size_t ws_size,
                              hipStream_t stream) {
    const float* q    = (const float*)d_in[0];
    const float* k    = (const float*)d_in[1];
    const float* v    = (const float*)d_in[2];
    const int*   mask = (const int*)d_in[3];
    float*       out  = (float*)d_out;

    attn_fwd<<<dim3(NQB * N_B * N_H), 256, 0, stream>>>(q, k, v, mask, out);
}